// Round 3
// baseline (1753.285 us; speedup 1.0000x reference)
//
#include <hip/hip_runtime.h>

// GCN: 100K nodes, 2.5M edges, dims 4 -> 32 -> (32x32 conv x3) -> 3.
// Round 3: atomic-free graph build (bucket counting-sort via LDS histograms +
// hierarchical scan) + per-bucket LDS-accumulator gather with the per-node MLP
// fused as epilogue. Zero device-scope atomics anywhere.
// Formulation: g[n] = dinv[n]*(h@W)[n]; S[n] = g[n] + sum_{src->n} g[src];
//              next h = relu(dinv*S + b).

constexpr int N_NODES = 100000;
constexpr int N_EDGES = 2500000;
constexpr int BUCKET  = 256;                          // nodes per dst-bucket
constexpr int NBUCK   = (N_NODES + BUCKET - 1) / BUCKET;   // 391
constexpr int NBLK    = 256;                          // build blocks
constexpr int CHUNK   = (N_EDGES + NBLK - 1) / NBLK;  // 9766 edges/block
constexpr int ROW     = 33;                           // padded LDS row stride

// ---- K1: per-block bucket histogram (LDS atomics only) ----
__global__ __launch_bounds__(256) void k_bincount(const int* __restrict__ ei,
                                                  int* __restrict__ blkbin) {
    __shared__ int hist[NBUCK];
    for (int i = threadIdx.x; i < NBUCK; i += 256) hist[i] = 0;
    __syncthreads();
    int beg = blockIdx.x * CHUNK;
    int end = min(beg + CHUNK, N_EDGES);
    for (int e = beg + threadIdx.x; e < end; e += 256) {
        int d = ei[N_EDGES + e];
        atomicAdd(&hist[d >> 8], 1);
    }
    __syncthreads();
    for (int i = threadIdx.x; i < NBUCK; i += 256)
        blkbin[i * NBLK + blockIdx.x] = hist[i];      // bin-major
}

// ---- K2a: bin totals (one wave per bin) ----
__global__ __launch_bounds__(256) void k_bintot(const int* __restrict__ blkbin,
                                                int* __restrict__ bintot) {
    int w = threadIdx.x >> 6, lane = threadIdx.x & 63;
    int bin = blockIdx.x * 4 + w;
    if (bin >= NBUCK) return;
    int s = 0;
    for (int k = lane; k < NBLK; k += 64) s += blkbin[bin * NBLK + k];
#pragma unroll
    for (int o = 32; o > 0; o >>= 1) s += __shfl_down(s, o);
    if (lane == 0) bintot[bin] = s;
}

// ---- K2b: exclusive scan of 391 bin totals -> binoff[0..NBUCK] ----
__global__ __launch_bounds__(512) void k_binscan(const int* __restrict__ bintot,
                                                 int* __restrict__ binoff) {
    __shared__ int sc[512];
    int tid = threadIdx.x;
    int v = (tid < NBUCK) ? bintot[tid] : 0;
    sc[tid] = v;
    __syncthreads();
#pragma unroll
    for (int o = 1; o < 512; o <<= 1) {
        int t = (tid >= o) ? sc[tid - o] : 0;
        __syncthreads();
        sc[tid] += t;
        __syncthreads();
    }
    if (tid < NBUCK) binoff[tid] = sc[tid] - v;
    if (tid == NBUCK - 1) binoff[NBUCK] = sc[tid];
}

// ---- K2c: per-bin exclusive scan over blocks -> blkoff (one wave per bin) ----
__global__ __launch_bounds__(256) void k_blkoff(const int* __restrict__ blkbin,
                                                const int* __restrict__ binoff,
                                                int* __restrict__ blkoff) {
    int w = threadIdx.x >> 6, lane = threadIdx.x & 63;
    int bin = blockIdx.x * 4 + w;
    if (bin >= NBUCK) return;
    int v[4];
#pragma unroll
    for (int i = 0; i < 4; ++i) v[i] = blkbin[bin * NBLK + lane * 4 + i];
    int mysum = v[0] + v[1] + v[2] + v[3];
    int pre = mysum;
#pragma unroll
    for (int o = 1; o < 64; o <<= 1) {
        int t = __shfl_up(pre, o);
        if (lane >= o) pre += t;
    }
    pre -= mysum;                                      // exclusive across lanes
    int run = binoff[bin] + pre;
#pragma unroll
    for (int i = 0; i < 4; ++i) {
        blkoff[bin * NBLK + lane * 4 + i] = run;
        run += v[i];
    }
}

// ---- K3: fill buckets; cursors in LDS (LDS returning atomics, no device atomics) ----
__global__ __launch_bounds__(256) void k_binfill(const int* __restrict__ ei,
                                                 const int* __restrict__ blkoff,
                                                 int* __restrict__ binned) {
    __shared__ int cur[NBUCK];
    for (int i = threadIdx.x; i < NBUCK; i += 256)
        cur[i] = blkoff[i * NBLK + blockIdx.x];
    __syncthreads();
    int beg = blockIdx.x * CHUNK;
    int end = min(beg + CHUNK, N_EDGES);
    for (int e = beg + threadIdx.x; e < end; e += 256) {
        int s = ei[e];
        int d = ei[N_EDGES + e];
        int pos = atomicAdd(&cur[d >> 8], 1);
        binned[pos] = (s << 8) | (d & 255);            // src<17b><<8 | dst_local<8b>
    }
}

// ---- K4: per-bucket degree -> dinv (LDS histogram) ----
__global__ __launch_bounds__(256) void k_deg(const int* __restrict__ binned,
                                             const int* __restrict__ binoff,
                                             float* __restrict__ dinv) {
    __shared__ int cnt[BUCKET];
    cnt[threadIdx.x] = 0;
    __syncthreads();
    int b = blockIdx.x;
    int beg = binoff[b], end = binoff[b + 1];
    for (int k = beg + threadIdx.x; k < end; k += 256)
        atomicAdd(&cnt[binned[k] & 255], 1);
    __syncthreads();
    int n = b * BUCKET + threadIdx.x;
    if (n < N_NODES) dinv[n] = rsqrtf((float)(cnt[threadIdx.x] + 1));  // +1 self-loop
}

// ---- fused: t = relu(x@Wfc1 + bfc1); g = dinv * (t@Wc1) ----
__global__ __launch_bounds__(256) void k_fc1_conv1(
        const float* __restrict__ x,
        const float* __restrict__ Wfc1, const float* __restrict__ bfc1,
        const float* __restrict__ Wc1, const float* __restrict__ dinv,
        float* __restrict__ g) {
    __shared__ float  sWf[128];
    __shared__ float  sbf[32];
    __shared__ float4 sW[256];
    if (threadIdx.x < 128) sWf[threadIdx.x] = Wfc1[threadIdx.x];
    if (threadIdx.x < 32)  sbf[threadIdx.x] = bfc1[threadIdx.x];
    sW[threadIdx.x] = ((const float4*)Wc1)[threadIdx.x];
    __syncthreads();

    int n = blockIdx.x * 256 + threadIdx.x;
    if (n >= N_NODES) return;

    float4 xin = *(const float4*)(x + (size_t)n * 4);
    float t[32];
#pragma unroll
    for (int j = 0; j < 32; ++j) {
        float a = fmaf(xin.x, sWf[j], sbf[j]);
        a = fmaf(xin.y, sWf[32 + j], a);
        a = fmaf(xin.z, sWf[64 + j], a);
        a = fmaf(xin.w, sWf[96 + j], a);
        t[j] = fmaxf(a, 0.0f);
    }
    float4 o[8];
#pragma unroll
    for (int q = 0; q < 8; ++q) o[q] = make_float4(0.f, 0.f, 0.f, 0.f);
#pragma unroll
    for (int k = 0; k < 32; ++k) {
        float a = t[k];
#pragma unroll
        for (int q = 0; q < 8; ++q) {
            float4 w = sW[k * 8 + q];
            o[q].x = fmaf(a, w.x, o[q].x);
            o[q].y = fmaf(a, w.y, o[q].y);
            o[q].z = fmaf(a, w.z, o[q].z);
            o[q].w = fmaf(a, w.w, o[q].w);
        }
    }
    float dv = dinv[n];
    float4* gp = (float4*)(g + (size_t)n * 32);
#pragma unroll
    for (int q = 0; q < 8; ++q)
        gp[q] = make_float4(dv * o[q].x, dv * o[q].y, dv * o[q].z, dv * o[q].w);
}

// ---- fused gather + mid-layer MLP. One block per bucket. ----
// acc[256][33] fp32 in LDS; 8 lanes/edge coalesced 128B g[src] reads; ds_add_f32.
__global__ __launch_bounds__(512) void k_gather_mid(
        const int* __restrict__ binned, const int* __restrict__ binoff,
        const float* __restrict__ dinv,
        const float* __restrict__ bprev, const float* __restrict__ W,
        const float* __restrict__ gin, float* __restrict__ gout) {
    __shared__ float  acc[BUCKET * ROW];   // 33 KB
    __shared__ float4 sW[256];
    __shared__ float  sb[32];
    if (threadIdx.x < 256) sW[threadIdx.x] = ((const float4*)W)[threadIdx.x];
    if (threadIdx.x < 32)  sb[threadIdx.x] = bprev[threadIdx.x];

    int b = blockIdx.x;
    int base = b * BUCKET;
    int nv = min(BUCKET, N_NODES - base);
    for (int i = threadIdx.x; i < nv * 32; i += 512)
        acc[(i >> 5) * ROW + (i & 31)] = gin[(size_t)base * 32 + i];   // self-loop init
    __syncthreads();

    int beg = binoff[b], end = binoff[b + 1];
    int sub = (threadIdx.x & 7) * 4;
    int grp = threadIdx.x >> 3;            // 0..63 -> 64 edges per block-iteration
    for (int k0 = beg; k0 < end; k0 += 64) {
        int k = k0 + grp;
        if (k < end) {
            int p = binned[k];
            int src = p >> 8;
            int dl = p & 255;
            float4 v = *(const float4*)(gin + (size_t)src * 32 + sub);
            float* a = acc + dl * ROW + sub;
            atomicAdd(a + 0, v.x);
            atomicAdd(a + 1, v.y);
            atomicAdd(a + 2, v.z);
            atomicAdd(a + 3, v.w);
        }
    }
    __syncthreads();

    // epilogue: 2 threads per node, 16 outputs each
    int node = threadIdx.x >> 1;
    int half = threadIdx.x & 1;
    if (node < nv) {
        float dv = dinv[base + node];
        float t[32];
#pragma unroll
        for (int k = 0; k < 32; ++k)
            t[k] = fmaxf(fmaf(dv, acc[node * ROW + k], sb[k]), 0.0f);
        float4 o[4];
#pragma unroll
        for (int q = 0; q < 4; ++q) o[q] = make_float4(0.f, 0.f, 0.f, 0.f);
#pragma unroll
        for (int k = 0; k < 32; ++k) {
            float aa = t[k];
#pragma unroll
            for (int q = 0; q < 4; ++q) {
                float4 w = sW[k * 8 + half * 4 + q];
                o[q].x = fmaf(aa, w.x, o[q].x);
                o[q].y = fmaf(aa, w.y, o[q].y);
                o[q].z = fmaf(aa, w.z, o[q].z);
                o[q].w = fmaf(aa, w.w, o[q].w);
            }
        }
        float4* gp = (float4*)(gout + (size_t)(base + node) * 32 + half * 16);
#pragma unroll
        for (int q = 0; q < 4; ++q)
            gp[q] = make_float4(dv * o[q].x, dv * o[q].y, dv * o[q].z, dv * o[q].w);
    }
}

// ---- fused gather + final layer: out = relu(dinv*S + bc3) @ Wfc2 + bfc2 ----
__global__ __launch_bounds__(512) void k_gather_out(
        const int* __restrict__ binned, const int* __restrict__ binoff,
        const float* __restrict__ dinv,
        const float* __restrict__ bc3, const float* __restrict__ Wfc2,
        const float* __restrict__ bfc2,
        const float* __restrict__ gin, float* __restrict__ out) {
    __shared__ float acc[BUCKET * ROW];
    __shared__ float sW[96];
    __shared__ float sb[32];
    __shared__ float sb2[3];
    if (threadIdx.x < 96) sW[threadIdx.x] = Wfc2[threadIdx.x];
    if (threadIdx.x < 32) sb[threadIdx.x] = bc3[threadIdx.x];
    if (threadIdx.x < 3)  sb2[threadIdx.x] = bfc2[threadIdx.x];

    int b = blockIdx.x;
    int base = b * BUCKET;
    int nv = min(BUCKET, N_NODES - base);
    for (int i = threadIdx.x; i < nv * 32; i += 512)
        acc[(i >> 5) * ROW + (i & 31)] = gin[(size_t)base * 32 + i];
    __syncthreads();

    int beg = binoff[b], end = binoff[b + 1];
    int sub = (threadIdx.x & 7) * 4;
    int grp = threadIdx.x >> 3;
    for (int k0 = beg; k0 < end; k0 += 64) {
        int k = k0 + grp;
        if (k < end) {
            int p = binned[k];
            int src = p >> 8;
            int dl = p & 255;
            float4 v = *(const float4*)(gin + (size_t)src * 32 + sub);
            float* a = acc + dl * ROW + sub;
            atomicAdd(a + 0, v.x);
            atomicAdd(a + 1, v.y);
            atomicAdd(a + 2, v.z);
            atomicAdd(a + 3, v.w);
        }
    }
    __syncthreads();

    if (threadIdx.x < (unsigned)nv) {
        int node = threadIdx.x;
        float dv = dinv[base + node];
        float t[32];
#pragma unroll
        for (int k = 0; k < 32; ++k)
            t[k] = fmaxf(fmaf(dv, acc[node * ROW + k], sb[k]), 0.0f);
        float o0 = sb2[0], o1 = sb2[1], o2 = sb2[2];
#pragma unroll
        for (int k = 0; k < 32; ++k) {
            o0 = fmaf(t[k], sW[k * 3 + 0], o0);
            o1 = fmaf(t[k], sW[k * 3 + 1], o1);
            o2 = fmaf(t[k], sW[k * 3 + 2], o2);
        }
        out[(size_t)(base + node) * 3 + 0] = o0;
        out[(size_t)(base + node) * 3 + 1] = o1;
        out[(size_t)(base + node) * 3 + 2] = o2;
    }
}

extern "C" void kernel_launch(void* const* d_in, const int* in_sizes, int n_in,
                              void* d_out, int out_size, void* d_ws, size_t ws_size,
                              hipStream_t stream) {
    const float* x    = (const float*)d_in[0];
    const int*   ei   = (const int*)d_in[1];
    const float* Wfc1 = (const float*)d_in[2];
    const float* bfc1 = (const float*)d_in[3];
    const float* Wc1  = (const float*)d_in[4];
    const float* bc1  = (const float*)d_in[5];
    const float* Wc2  = (const float*)d_in[6];
    const float* bc2  = (const float*)d_in[7];
    const float* Wc3  = (const float*)d_in[8];
    const float* bc3  = (const float*)d_in[9];
    const float* Wfc2 = (const float*)d_in[10];
    const float* bfc2 = (const float*)d_in[11];
    float* out = (float*)d_out;

    char* ws = (char*)d_ws;
    const size_t feat_bytes = (size_t)N_NODES * 32 * sizeof(float);   // 12.8 MB
    size_t off = 0;
    float* gA     = (float*)(ws + off); off += feat_bytes;
    float* gB     = (float*)(ws + off); off += feat_bytes;
    int*   binned = (int*)  (ws + off); off += (size_t)N_EDGES * sizeof(int);
    float* dinv   = (float*)(ws + off); off += (size_t)N_NODES * sizeof(float);
    int*   blkbin = (int*)  (ws + off); off += (size_t)NBUCK * NBLK * sizeof(int);
    int*   blkoff = (int*)  (ws + off); off += (size_t)NBUCK * NBLK * sizeof(int);
    int*   bintot = (int*)  (ws + off); off += (size_t)NBUCK * sizeof(int);
    int*   binoff = (int*)  (ws + off); off += (size_t)(NBUCK + 1) * sizeof(int);

    const int nb_wave = (NBUCK + 3) / 4;   // 98 blocks of 4 waves

    k_bincount<<<NBLK, 256, 0, stream>>>(ei, blkbin);
    k_bintot<<<nb_wave, 256, 0, stream>>>(blkbin, bintot);
    k_binscan<<<1, 512, 0, stream>>>(bintot, binoff);
    k_blkoff<<<nb_wave, 256, 0, stream>>>(blkbin, binoff, blkoff);
    k_binfill<<<NBLK, 256, 0, stream>>>(ei, blkoff, binned);
    k_deg<<<NBUCK, 256, 0, stream>>>(binned, binoff, dinv);

    k_fc1_conv1<<<(N_NODES + 255) / 256, 256, 0, stream>>>(x, Wfc1, bfc1, Wc1, dinv, gA);
    k_gather_mid<<<NBUCK, 512, 0, stream>>>(binned, binoff, dinv, bc1, Wc2, gA, gB);
    k_gather_mid<<<NBUCK, 512, 0, stream>>>(binned, binoff, dinv, bc2, Wc3, gB, gA);
    k_gather_out<<<NBUCK, 512, 0, stream>>>(binned, binoff, dinv, bc3, Wfc2, bfc2, gA, out);
}

// Round 4
// 363.451 us; speedup vs baseline: 4.8240x; 4.8240x over previous
//
#include <hip/hip_runtime.h>

// GCN: 100K nodes, 2.5M edges, dims 4 -> 32 -> (32x32 conv x3) -> 3.
// Round 4: hybrid of the two measured-fast halves.
//  - Build: atomic-free bucket counting sort (R3) + NEW per-bucket counting sort
//    by dst_local -> true per-node CSR (rowptr, csr_src) + dinv. LDS atomics only.
//  - Aggregate: R2's register-accumulate gather (800K threads, 8/node) + cheap
//    per-node MLP kernels. (R3's per-bucket LDS gather was latency-starved:
//    391 blocks, 26% occupancy, 538us. R2's was ~60us.)
// Formulation: g[n] = dinv[n]*(h@W)[n]; S[n] = g[n] + sum_{src->n} g[src];
//              next h = relu(dinv*S + b).

constexpr int N_NODES = 100000;
constexpr int N_EDGES = 2500000;
constexpr int BUCKET  = 256;                               // nodes per dst-bucket
constexpr int NBUCK   = (N_NODES + BUCKET - 1) / BUCKET;   // 391
constexpr int NBLK    = 256;                               // build blocks
constexpr int CHUNK   = (N_EDGES + NBLK - 1) / NBLK;       // 9766 edges/block

// ---- K1: per-block bucket histogram (LDS atomics only) ----
__global__ __launch_bounds__(256) void k_bincount(const int* __restrict__ ei,
                                                  int* __restrict__ blkbin) {
    __shared__ int hist[NBUCK];
    for (int i = threadIdx.x; i < NBUCK; i += 256) hist[i] = 0;
    __syncthreads();
    int beg = blockIdx.x * CHUNK;
    int end = min(beg + CHUNK, N_EDGES);
    for (int e = beg + threadIdx.x; e < end; e += 256) {
        int d = ei[N_EDGES + e];
        atomicAdd(&hist[d >> 8], 1);
    }
    __syncthreads();
    for (int i = threadIdx.x; i < NBUCK; i += 256)
        blkbin[i * NBLK + blockIdx.x] = hist[i];      // bin-major
}

// ---- K2a: bin totals (one wave per bin) ----
__global__ __launch_bounds__(256) void k_bintot(const int* __restrict__ blkbin,
                                                int* __restrict__ bintot) {
    int w = threadIdx.x >> 6, lane = threadIdx.x & 63;
    int bin = blockIdx.x * 4 + w;
    if (bin >= NBUCK) return;
    int s = 0;
    for (int k = lane; k < NBLK; k += 64) s += blkbin[bin * NBLK + k];
#pragma unroll
    for (int o = 32; o > 0; o >>= 1) s += __shfl_down(s, o);
    if (lane == 0) bintot[bin] = s;
}

// ---- K2b: exclusive scan of 391 bin totals -> binoff[0..NBUCK] ----
__global__ __launch_bounds__(512) void k_binscan(const int* __restrict__ bintot,
                                                 int* __restrict__ binoff) {
    __shared__ int sc[512];
    int tid = threadIdx.x;
    int v = (tid < NBUCK) ? bintot[tid] : 0;
    sc[tid] = v;
    __syncthreads();
#pragma unroll
    for (int o = 1; o < 512; o <<= 1) {
        int t = (tid >= o) ? sc[tid - o] : 0;
        __syncthreads();
        sc[tid] += t;
        __syncthreads();
    }
    if (tid < NBUCK) binoff[tid] = sc[tid] - v;
    if (tid == NBUCK - 1) binoff[NBUCK] = sc[tid];
}

// ---- K2c: per-bin exclusive scan over blocks -> blkoff (one wave per bin) ----
__global__ __launch_bounds__(256) void k_blkoff(const int* __restrict__ blkbin,
                                                const int* __restrict__ binoff,
                                                int* __restrict__ blkoff) {
    int w = threadIdx.x >> 6, lane = threadIdx.x & 63;
    int bin = blockIdx.x * 4 + w;
    if (bin >= NBUCK) return;
    int v[4];
#pragma unroll
    for (int i = 0; i < 4; ++i) v[i] = blkbin[bin * NBLK + lane * 4 + i];
    int mysum = v[0] + v[1] + v[2] + v[3];
    int pre = mysum;
#pragma unroll
    for (int o = 1; o < 64; o <<= 1) {
        int t = __shfl_up(pre, o);
        if (lane >= o) pre += t;
    }
    pre -= mysum;                                      // exclusive across lanes
    int run = binoff[bin] + pre;
#pragma unroll
    for (int i = 0; i < 4; ++i) {
        blkoff[bin * NBLK + lane * 4 + i] = run;
        run += v[i];
    }
}

// ---- K3: fill buckets; cursors in LDS ----
__global__ __launch_bounds__(256) void k_binfill(const int* __restrict__ ei,
                                                 const int* __restrict__ blkoff,
                                                 int* __restrict__ binned) {
    __shared__ int cur[NBUCK];
    for (int i = threadIdx.x; i < NBUCK; i += 256)
        cur[i] = blkoff[i * NBLK + blockIdx.x];
    __syncthreads();
    int beg = blockIdx.x * CHUNK;
    int end = min(beg + CHUNK, N_EDGES);
    for (int e = beg + threadIdx.x; e < end; e += 256) {
        int s = ei[e];
        int d = ei[N_EDGES + e];
        int pos = atomicAdd(&cur[d >> 8], 1);
        binned[pos] = (s << 8) | (d & 255);            // src<17b><<8 | dst_local<8b>
    }
}

// ---- K4: within-bucket counting sort by dst_local -> per-node CSR + dinv ----
// One block per bucket: LDS histogram -> LDS scan -> LDS-cursor scatter.
__global__ __launch_bounds__(256) void k_sortdeg(const int* __restrict__ binned,
                                                 const int* __restrict__ binoff,
                                                 int* __restrict__ csr_src,
                                                 int* __restrict__ rowptr,
                                                 float* __restrict__ dinv) {
    __shared__ int cnt[BUCKET];
    __shared__ int sc[BUCKET];
    __shared__ int cur[BUCKET];
    int tid = threadIdx.x;
    int b = blockIdx.x;
    int beg = binoff[b], end = binoff[b + 1];

    cnt[tid] = 0;
    __syncthreads();
    for (int k = beg + tid; k < end; k += 256)
        atomicAdd(&cnt[binned[k] & 255], 1);
    __syncthreads();

    // inclusive scan of cnt -> sc
    int v = cnt[tid];
    sc[tid] = v;
    __syncthreads();
#pragma unroll
    for (int o = 1; o < 256; o <<= 1) {
        int t = (tid >= o) ? sc[tid - o] : 0;
        __syncthreads();
        sc[tid] += t;
        __syncthreads();
    }
    int excl = sc[tid] - v;                 // local exclusive offset
    cur[tid] = excl;
    int n = b * BUCKET + tid;
    if (n < N_NODES) {
        rowptr[n] = beg + excl;
        dinv[n] = rsqrtf((float)(v + 1));   // +1 self-loop
        if (n == N_NODES - 1) rowptr[N_NODES] = end;
    }
    __syncthreads();

    for (int k = beg + tid; k < end; k += 256) {
        int p = binned[k];
        int pos = atomicAdd(&cur[p & 255], 1);
        csr_src[beg + pos] = p >> 8;
    }
}

// ---- fused: t = relu(x@Wfc1 + bfc1); g = dinv * (t@Wc1) ----
__global__ __launch_bounds__(256) void k_fc1_conv1(
        const float* __restrict__ x,
        const float* __restrict__ Wfc1, const float* __restrict__ bfc1,
        const float* __restrict__ Wc1, const float* __restrict__ dinv,
        float* __restrict__ g) {
    __shared__ float  sWf[128];
    __shared__ float  sbf[32];
    __shared__ float4 sW[256];
    if (threadIdx.x < 128) sWf[threadIdx.x] = Wfc1[threadIdx.x];
    if (threadIdx.x < 32)  sbf[threadIdx.x] = bfc1[threadIdx.x];
    sW[threadIdx.x] = ((const float4*)Wc1)[threadIdx.x];
    __syncthreads();

    int n = blockIdx.x * 256 + threadIdx.x;
    if (n >= N_NODES) return;

    float4 xin = *(const float4*)(x + (size_t)n * 4);
    float t[32];
#pragma unroll
    for (int j = 0; j < 32; ++j) {
        float a = fmaf(xin.x, sWf[j], sbf[j]);
        a = fmaf(xin.y, sWf[32 + j], a);
        a = fmaf(xin.z, sWf[64 + j], a);
        a = fmaf(xin.w, sWf[96 + j], a);
        t[j] = fmaxf(a, 0.0f);
    }
    float4 o[8];
#pragma unroll
    for (int q = 0; q < 8; ++q) o[q] = make_float4(0.f, 0.f, 0.f, 0.f);
#pragma unroll
    for (int k = 0; k < 32; ++k) {
        float a = t[k];
#pragma unroll
        for (int q = 0; q < 8; ++q) {
            float4 w = sW[k * 8 + q];
            o[q].x = fmaf(a, w.x, o[q].x);
            o[q].y = fmaf(a, w.y, o[q].y);
            o[q].z = fmaf(a, w.z, o[q].z);
            o[q].w = fmaf(a, w.w, o[q].w);
        }
    }
    float dv = dinv[n];
    float4* gp = (float4*)(g + (size_t)n * 32);
#pragma unroll
    for (int q = 0; q < 8; ++q)
        gp[q] = make_float4(dv * o[q].x, dv * o[q].y, dv * o[q].z, dv * o[q].w);
}

// ---- gather: S[n] = g[n] + sum_{k in [rowptr[n],rowptr[n+1])} g[csr_src[k]] ----
// 8 threads per node; each thread owns a float4 slice; octet read = 128B coalesced.
__global__ __launch_bounds__(256) void k_gather(const int* __restrict__ rowptr,
                                                const int* __restrict__ csr_src,
                                                const float* __restrict__ g,
                                                float* __restrict__ S) {
    int tid = blockIdx.x * 256 + threadIdx.x;
    int n = tid >> 3;
    if (n >= N_NODES) return;
    int sub = (tid & 7) * 4;
    int beg = rowptr[n];
    int end = rowptr[n + 1];
    float4 acc = *(const float4*)(g + (size_t)n * 32 + sub);   // self-loop term
    for (int k = beg; k < end; ++k) {
        int s = csr_src[k];
        float4 v = *(const float4*)(g + (size_t)s * 32 + sub);
        acc.x += v.x; acc.y += v.y; acc.z += v.z; acc.w += v.w;
    }
    *(float4*)(S + (size_t)n * 32 + sub) = acc;
}

// ---- mid layer: t = relu(dinv*S + b_prev); g = dinv*(t@W) ----
__global__ __launch_bounds__(256) void k_mid(
        const float* __restrict__ bprev, const float* __restrict__ W,
        const float* __restrict__ dinv,
        const float* __restrict__ S, float* __restrict__ g) {
    __shared__ float  sb[32];
    __shared__ float4 sW[256];
    if (threadIdx.x < 32) sb[threadIdx.x] = bprev[threadIdx.x];
    sW[threadIdx.x] = ((const float4*)W)[threadIdx.x];
    __syncthreads();

    int n = blockIdx.x * 256 + threadIdx.x;
    if (n >= N_NODES) return;

    float dv = dinv[n];
    const float4* Sp = (const float4*)(S + (size_t)n * 32);
    float t[32];
#pragma unroll
    for (int q = 0; q < 8; ++q) {
        float4 v = Sp[q];
        t[q * 4 + 0] = fmaxf(fmaf(dv, v.x, sb[q * 4 + 0]), 0.0f);
        t[q * 4 + 1] = fmaxf(fmaf(dv, v.y, sb[q * 4 + 1]), 0.0f);
        t[q * 4 + 2] = fmaxf(fmaf(dv, v.z, sb[q * 4 + 2]), 0.0f);
        t[q * 4 + 3] = fmaxf(fmaf(dv, v.w, sb[q * 4 + 3]), 0.0f);
    }

    float4 o[8];
#pragma unroll
    for (int q = 0; q < 8; ++q) o[q] = make_float4(0.f, 0.f, 0.f, 0.f);
#pragma unroll
    for (int k = 0; k < 32; ++k) {
        float a = t[k];
#pragma unroll
        for (int q = 0; q < 8; ++q) {
            float4 w = sW[k * 8 + q];
            o[q].x = fmaf(a, w.x, o[q].x);
            o[q].y = fmaf(a, w.y, o[q].y);
            o[q].z = fmaf(a, w.z, o[q].z);
            o[q].w = fmaf(a, w.w, o[q].w);
        }
    }

    float4* gp = (float4*)(g + (size_t)n * 32);
#pragma unroll
    for (int q = 0; q < 8; ++q)
        gp[q] = make_float4(dv * o[q].x, dv * o[q].y, dv * o[q].z, dv * o[q].w);
}

// ---- output: t = relu(dinv*S + bc3); out = t@Wfc2 + bfc2 ----
__global__ __launch_bounds__(256) void k_out(
        const float* __restrict__ bc3, const float* __restrict__ Wfc2,
        const float* __restrict__ bfc2, const float* __restrict__ dinv,
        const float* __restrict__ S, float* __restrict__ out) {
    __shared__ float sb[32];
    __shared__ float sW[96];   // 32x3
    __shared__ float sb2[3];
    if (threadIdx.x < 32) sb[threadIdx.x] = bc3[threadIdx.x];
    if (threadIdx.x < 96) sW[threadIdx.x] = Wfc2[threadIdx.x];
    if (threadIdx.x < 3)  sb2[threadIdx.x] = bfc2[threadIdx.x];
    __syncthreads();

    int n = blockIdx.x * 256 + threadIdx.x;
    if (n >= N_NODES) return;

    float dv = dinv[n];
    const float4* Sp = (const float4*)(S + (size_t)n * 32);
    float t[32];
#pragma unroll
    for (int q = 0; q < 8; ++q) {
        float4 v = Sp[q];
        t[q * 4 + 0] = fmaxf(fmaf(dv, v.x, sb[q * 4 + 0]), 0.0f);
        t[q * 4 + 1] = fmaxf(fmaf(dv, v.y, sb[q * 4 + 1]), 0.0f);
        t[q * 4 + 2] = fmaxf(fmaf(dv, v.z, sb[q * 4 + 2]), 0.0f);
        t[q * 4 + 3] = fmaxf(fmaf(dv, v.w, sb[q * 4 + 3]), 0.0f);
    }

    float o0 = sb2[0], o1 = sb2[1], o2 = sb2[2];
#pragma unroll
    for (int k = 0; k < 32; ++k) {
        o0 = fmaf(t[k], sW[k * 3 + 0], o0);
        o1 = fmaf(t[k], sW[k * 3 + 1], o1);
        o2 = fmaf(t[k], sW[k * 3 + 2], o2);
    }
    out[(size_t)n * 3 + 0] = o0;
    out[(size_t)n * 3 + 1] = o1;
    out[(size_t)n * 3 + 2] = o2;
}

extern "C" void kernel_launch(void* const* d_in, const int* in_sizes, int n_in,
                              void* d_out, int out_size, void* d_ws, size_t ws_size,
                              hipStream_t stream) {
    const float* x    = (const float*)d_in[0];
    const int*   ei   = (const int*)d_in[1];
    const float* Wfc1 = (const float*)d_in[2];
    const float* bfc1 = (const float*)d_in[3];
    const float* Wc1  = (const float*)d_in[4];
    const float* bc1  = (const float*)d_in[5];
    const float* Wc2  = (const float*)d_in[6];
    const float* bc2  = (const float*)d_in[7];
    const float* Wc3  = (const float*)d_in[8];
    const float* bc3  = (const float*)d_in[9];
    const float* Wfc2 = (const float*)d_in[10];
    const float* bfc2 = (const float*)d_in[11];
    float* out = (float*)d_out;

    char* ws = (char*)d_ws;
    const size_t feat_bytes = (size_t)N_NODES * 32 * sizeof(float);   // 12.8 MB
    size_t off = 0;
    float* S       = (float*)(ws + off); off += feat_bytes;
    float* g       = (float*)(ws + off); off += feat_bytes;
    int*   binned  = (int*)  (ws + off); off += (size_t)N_EDGES * sizeof(int);   // 10 MB
    int*   csr_src = (int*)  (ws + off); off += (size_t)N_EDGES * sizeof(int);   // 10 MB
    float* dinv    = (float*)(ws + off); off += (size_t)N_NODES * sizeof(float);
    int*   rowptr  = (int*)  (ws + off); off += (size_t)(N_NODES + 1) * sizeof(int);
    int*   blkbin  = (int*)  (ws + off); off += (size_t)NBUCK * NBLK * sizeof(int);
    int*   blkoff  = (int*)  (ws + off); off += (size_t)NBUCK * NBLK * sizeof(int);
    int*   bintot  = (int*)  (ws + off); off += (size_t)NBUCK * sizeof(int);
    int*   binoff  = (int*)  (ws + off); off += (size_t)(NBUCK + 1) * sizeof(int);

    const int nb_wave = (NBUCK + 3) / 4;         // 98
    const int nb_n = (N_NODES + 255) / 256;      // 391
    const int nb_g = (N_NODES * 8 + 255) / 256;  // 3125

    k_bincount<<<NBLK, 256, 0, stream>>>(ei, blkbin);
    k_bintot<<<nb_wave, 256, 0, stream>>>(blkbin, bintot);
    k_binscan<<<1, 512, 0, stream>>>(bintot, binoff);
    k_blkoff<<<nb_wave, 256, 0, stream>>>(blkbin, binoff, blkoff);
    k_binfill<<<NBLK, 256, 0, stream>>>(ei, blkoff, binned);
    k_sortdeg<<<NBUCK, 256, 0, stream>>>(binned, binoff, csr_src, rowptr, dinv);

    k_fc1_conv1<<<nb_n, 256, 0, stream>>>(x, Wfc1, bfc1, Wc1, dinv, g);
    k_gather<<<nb_g, 256, 0, stream>>>(rowptr, csr_src, g, S);
    k_mid<<<nb_n, 256, 0, stream>>>(bc1, Wc2, dinv, S, g);
    k_gather<<<nb_g, 256, 0, stream>>>(rowptr, csr_src, g, S);
    k_mid<<<nb_n, 256, 0, stream>>>(bc2, Wc3, dinv, S, g);
    k_gather<<<nb_g, 256, 0, stream>>>(rowptr, csr_src, g, S);
    k_out<<<nb_n, 256, 0, stream>>>(bc3, Wfc2, bfc2, dinv, S, out);
}

// Round 5
// 271.245 us; speedup vs baseline: 6.4638x; 1.3399x over previous
//
#include <hip/hip_runtime.h>
#include <hip/hip_fp16.h>

// GCN: 100K nodes, 2.5M edges, dims 4 -> 32 -> (32x32 conv x3) -> 3.
// Round 5: (a) g stored fp16 (64B/row) -> halves the random-gather footprint
// (R4 FETCH showed every XCD pulls all of g: 8x12.8MB~=127MB; fp16 -> ~60MB);
// (b) edge loop unrolled x4 (4 independent loads in flight);
// (c) per-node MLP fused into the gather epilogue via LDS (kills k_mid x2,
// k_out, and 77MB of S round-trips). Accumulation stays fp32.
// Build (atomic-free counting sort -> CSR) kept from R4 (measured off-path).

constexpr int N_NODES = 100000;
constexpr int N_EDGES = 2500000;
constexpr int BUCKET  = 256;
constexpr int NBUCK   = (N_NODES + BUCKET - 1) / BUCKET;   // 391
constexpr int NBLK    = 256;
constexpr int CHUNK   = (N_EDGES + NBLK - 1) / NBLK;       // 9766

// ================= build (unchanged from R4) =================
__global__ __launch_bounds__(256) void k_bincount(const int* __restrict__ ei,
                                                  int* __restrict__ blkbin) {
    __shared__ int hist[NBUCK];
    for (int i = threadIdx.x; i < NBUCK; i += 256) hist[i] = 0;
    __syncthreads();
    int beg = blockIdx.x * CHUNK;
    int end = min(beg + CHUNK, N_EDGES);
    for (int e = beg + threadIdx.x; e < end; e += 256) {
        int d = ei[N_EDGES + e];
        atomicAdd(&hist[d >> 8], 1);
    }
    __syncthreads();
    for (int i = threadIdx.x; i < NBUCK; i += 256)
        blkbin[i * NBLK + blockIdx.x] = hist[i];
}

__global__ __launch_bounds__(256) void k_bintot(const int* __restrict__ blkbin,
                                                int* __restrict__ bintot) {
    int w = threadIdx.x >> 6, lane = threadIdx.x & 63;
    int bin = blockIdx.x * 4 + w;
    if (bin >= NBUCK) return;
    int s = 0;
    for (int k = lane; k < NBLK; k += 64) s += blkbin[bin * NBLK + k];
#pragma unroll
    for (int o = 32; o > 0; o >>= 1) s += __shfl_down(s, o);
    if (lane == 0) bintot[bin] = s;
}

__global__ __launch_bounds__(512) void k_binscan(const int* __restrict__ bintot,
                                                 int* __restrict__ binoff) {
    __shared__ int sc[512];
    int tid = threadIdx.x;
    int v = (tid < NBUCK) ? bintot[tid] : 0;
    sc[tid] = v;
    __syncthreads();
#pragma unroll
    for (int o = 1; o < 512; o <<= 1) {
        int t = (tid >= o) ? sc[tid - o] : 0;
        __syncthreads();
        sc[tid] += t;
        __syncthreads();
    }
    if (tid < NBUCK) binoff[tid] = sc[tid] - v;
    if (tid == NBUCK - 1) binoff[NBUCK] = sc[tid];
}

__global__ __launch_bounds__(256) void k_blkoff(const int* __restrict__ blkbin,
                                                const int* __restrict__ binoff,
                                                int* __restrict__ blkoff) {
    int w = threadIdx.x >> 6, lane = threadIdx.x & 63;
    int bin = blockIdx.x * 4 + w;
    if (bin >= NBUCK) return;
    int v[4];
#pragma unroll
    for (int i = 0; i < 4; ++i) v[i] = blkbin[bin * NBLK + lane * 4 + i];
    int mysum = v[0] + v[1] + v[2] + v[3];
    int pre = mysum;
#pragma unroll
    for (int o = 1; o < 64; o <<= 1) {
        int t = __shfl_up(pre, o);
        if (lane >= o) pre += t;
    }
    pre -= mysum;
    int run = binoff[bin] + pre;
#pragma unroll
    for (int i = 0; i < 4; ++i) {
        blkoff[bin * NBLK + lane * 4 + i] = run;
        run += v[i];
    }
}

__global__ __launch_bounds__(256) void k_binfill(const int* __restrict__ ei,
                                                 const int* __restrict__ blkoff,
                                                 int* __restrict__ binned) {
    __shared__ int cur[NBUCK];
    for (int i = threadIdx.x; i < NBUCK; i += 256)
        cur[i] = blkoff[i * NBLK + blockIdx.x];
    __syncthreads();
    int beg = blockIdx.x * CHUNK;
    int end = min(beg + CHUNK, N_EDGES);
    for (int e = beg + threadIdx.x; e < end; e += 256) {
        int s = ei[e];
        int d = ei[N_EDGES + e];
        int pos = atomicAdd(&cur[d >> 8], 1);
        binned[pos] = (s << 8) | (d & 255);
    }
}

__global__ __launch_bounds__(256) void k_sortdeg(const int* __restrict__ binned,
                                                 const int* __restrict__ binoff,
                                                 int* __restrict__ csr_src,
                                                 int* __restrict__ rowptr,
                                                 float* __restrict__ dinv) {
    __shared__ int cnt[BUCKET];
    __shared__ int sc[BUCKET];
    __shared__ int cur[BUCKET];
    int tid = threadIdx.x;
    int b = blockIdx.x;
    int beg = binoff[b], end = binoff[b + 1];

    cnt[tid] = 0;
    __syncthreads();
    for (int k = beg + tid; k < end; k += 256)
        atomicAdd(&cnt[binned[k] & 255], 1);
    __syncthreads();

    int v = cnt[tid];
    sc[tid] = v;
    __syncthreads();
#pragma unroll
    for (int o = 1; o < 256; o <<= 1) {
        int t = (tid >= o) ? sc[tid - o] : 0;
        __syncthreads();
        sc[tid] += t;
        __syncthreads();
    }
    int excl = sc[tid] - v;
    cur[tid] = excl;
    int n = b * BUCKET + tid;
    if (n < N_NODES) {
        rowptr[n] = beg + excl;
        dinv[n] = rsqrtf((float)(v + 1));
        if (n == N_NODES - 1) rowptr[N_NODES] = end;
    }
    __syncthreads();

    for (int k = beg + tid; k < end; k += 256) {
        int p = binned[k];
        int pos = atomicAdd(&cur[p & 255], 1);
        csr_src[beg + pos] = p >> 8;
    }
}

// ================= dense layers =================
// helper: pack 8 floats -> 8 halfs (16B) at p
__device__ inline void store_half8(__half* p, const float* v) {
    __half2 h[4];
#pragma unroll
    for (int i = 0; i < 4; ++i)
        h[i] = __floats2half2_rn(v[2 * i], v[2 * i + 1]);
    *(float4*)p = *(float4*)h;
}

// t = relu(x@Wfc1 + bfc1); g = half( dinv * (t@Wc1) )
__global__ __launch_bounds__(256) void k_fc1_conv1(
        const float* __restrict__ x,
        const float* __restrict__ Wfc1, const float* __restrict__ bfc1,
        const float* __restrict__ Wc1, const float* __restrict__ dinv,
        __half* __restrict__ g) {
    __shared__ float  sWf[128];
    __shared__ float  sbf[32];
    __shared__ float4 sW[256];
    if (threadIdx.x < 128) sWf[threadIdx.x] = Wfc1[threadIdx.x];
    if (threadIdx.x < 32)  sbf[threadIdx.x] = bfc1[threadIdx.x];
    sW[threadIdx.x] = ((const float4*)Wc1)[threadIdx.x];
    __syncthreads();

    int n = blockIdx.x * 256 + threadIdx.x;
    if (n >= N_NODES) return;

    float4 xin = *(const float4*)(x + (size_t)n * 4);
    float t[32];
#pragma unroll
    for (int j = 0; j < 32; ++j) {
        float a = fmaf(xin.x, sWf[j], sbf[j]);
        a = fmaf(xin.y, sWf[32 + j], a);
        a = fmaf(xin.z, sWf[64 + j], a);
        a = fmaf(xin.w, sWf[96 + j], a);
        t[j] = fmaxf(a, 0.0f);
    }
    float o[32];
#pragma unroll
    for (int j = 0; j < 32; ++j) o[j] = 0.f;
#pragma unroll
    for (int k = 0; k < 32; ++k) {
        float a = t[k];
#pragma unroll
        for (int q = 0; q < 8; ++q) {
            float4 w = sW[k * 8 + q];
            o[q * 4 + 0] = fmaf(a, w.x, o[q * 4 + 0]);
            o[q * 4 + 1] = fmaf(a, w.y, o[q * 4 + 1]);
            o[q * 4 + 2] = fmaf(a, w.z, o[q * 4 + 2]);
            o[q * 4 + 3] = fmaf(a, w.w, o[q * 4 + 3]);
        }
    }
    float dv = dinv[n];
#pragma unroll
    for (int j = 0; j < 32; ++j) o[j] *= dv;
    __half* gp = g + (size_t)n * 32;
    store_half8(gp,      o);
    store_half8(gp + 8,  o + 8);
    store_half8(gp + 16, o + 16);
    store_half8(gp + 24, o + 24);
}

// convert 16B of halfs (as float4) -> 8 floats added into acc
__device__ inline void acc_half8(float* acc, float4 raw) {
    __half2* hp = (__half2*)&raw;
#pragma unroll
    for (int i = 0; i < 4; ++i) {
        float2 f = __half22float2(hp[i]);
        acc[2 * i]     += f.x;
        acc[2 * i + 1] += f.y;
    }
}

// ---- fused gather + mid MLP: 4 threads/node, 64 nodes/block ----
// S[n] = g[n] + sum g[src]; t = relu(dinv*S + b); gout = half(dinv * t@W)
__global__ __launch_bounds__(256) void k_gather_mid(
        const int* __restrict__ rowptr, const int* __restrict__ csr_src,
        const __half* __restrict__ gin, const float* __restrict__ dinv,
        const float* __restrict__ b, const float* __restrict__ W,
        __half* __restrict__ gout) {
    __shared__ float sS[64 * 33];
    __shared__ float sW[1024];
    __shared__ float sb[32];
    for (int i = threadIdx.x; i < 1024; i += 256) sW[i] = W[i];
    if (threadIdx.x < 32) sb[threadIdx.x] = b[threadIdx.x];

    int nl = threadIdx.x >> 2;                 // node within block
    int sub = threadIdx.x & 3;                 // 8-feature slice
    int n = blockIdx.x * 64 + nl;
    float acc[8];
    if (n < N_NODES) {
        float4 self = *(const float4*)(gin + (size_t)n * 32 + sub * 8);
        {
            __half2* hp = (__half2*)&self;
#pragma unroll
            for (int i = 0; i < 4; ++i) {
                float2 f = __half22float2(hp[i]);
                acc[2 * i] = f.x;
                acc[2 * i + 1] = f.y;
            }
        }
        int beg = rowptr[n], end = rowptr[n + 1];
        int k = beg;
        for (; k + 3 < end; k += 4) {
            int s0 = csr_src[k], s1 = csr_src[k + 1];
            int s2 = csr_src[k + 2], s3 = csr_src[k + 3];
            float4 r0 = *(const float4*)(gin + (size_t)s0 * 32 + sub * 8);
            float4 r1 = *(const float4*)(gin + (size_t)s1 * 32 + sub * 8);
            float4 r2 = *(const float4*)(gin + (size_t)s2 * 32 + sub * 8);
            float4 r3 = *(const float4*)(gin + (size_t)s3 * 32 + sub * 8);
            acc_half8(acc, r0); acc_half8(acc, r1);
            acc_half8(acc, r2); acc_half8(acc, r3);
        }
        for (; k < end; ++k) {
            int s = csr_src[k];
            float4 r = *(const float4*)(gin + (size_t)s * 32 + sub * 8);
            acc_half8(acc, r);
        }
#pragma unroll
        for (int i = 0; i < 8; ++i) sS[nl * 33 + sub * 8 + i] = acc[i];
    }
    __syncthreads();

    if (n >= N_NODES) return;
    float dv = dinv[n];
    float t[32];
#pragma unroll
    for (int kk = 0; kk < 32; ++kk)
        t[kk] = fmaxf(fmaf(dv, sS[nl * 33 + kk], sb[kk]), 0.0f);
    float o[8];
#pragma unroll
    for (int j = 0; j < 8; ++j) o[j] = 0.f;
#pragma unroll
    for (int kk = 0; kk < 32; ++kk) {
        float a = t[kk];
#pragma unroll
        for (int j = 0; j < 8; ++j)
            o[j] = fmaf(a, sW[kk * 32 + sub * 8 + j], o[j]);
    }
#pragma unroll
    for (int j = 0; j < 8; ++j) o[j] *= dv;
    store_half8(gout + (size_t)n * 32 + sub * 8, o);
}

// ---- fused gather + final layer: out = relu(dinv*S + bc3) @ Wfc2 + bfc2 ----
__global__ __launch_bounds__(256) void k_gather_out(
        const int* __restrict__ rowptr, const int* __restrict__ csr_src,
        const __half* __restrict__ gin, const float* __restrict__ dinv,
        const float* __restrict__ bc3, const float* __restrict__ Wfc2,
        const float* __restrict__ bfc2, float* __restrict__ out) {
    __shared__ float sS[64 * 33];
    __shared__ float sW[96];
    __shared__ float sb[32];
    __shared__ float sb2[3];
    if (threadIdx.x < 96) sW[threadIdx.x] = Wfc2[threadIdx.x];
    if (threadIdx.x < 32) sb[threadIdx.x] = bc3[threadIdx.x];
    if (threadIdx.x < 3)  sb2[threadIdx.x] = bfc2[threadIdx.x];

    int nl = threadIdx.x >> 2;
    int sub = threadIdx.x & 3;
    int n = blockIdx.x * 64 + nl;
    float acc[8];
    if (n < N_NODES) {
        float4 self = *(const float4*)(gin + (size_t)n * 32 + sub * 8);
        {
            __half2* hp = (__half2*)&self;
#pragma unroll
            for (int i = 0; i < 4; ++i) {
                float2 f = __half22float2(hp[i]);
                acc[2 * i] = f.x;
                acc[2 * i + 1] = f.y;
            }
        }
        int beg = rowptr[n], end = rowptr[n + 1];
        int k = beg;
        for (; k + 3 < end; k += 4) {
            int s0 = csr_src[k], s1 = csr_src[k + 1];
            int s2 = csr_src[k + 2], s3 = csr_src[k + 3];
            float4 r0 = *(const float4*)(gin + (size_t)s0 * 32 + sub * 8);
            float4 r1 = *(const float4*)(gin + (size_t)s1 * 32 + sub * 8);
            float4 r2 = *(const float4*)(gin + (size_t)s2 * 32 + sub * 8);
            float4 r3 = *(const float4*)(gin + (size_t)s3 * 32 + sub * 8);
            acc_half8(acc, r0); acc_half8(acc, r1);
            acc_half8(acc, r2); acc_half8(acc, r3);
        }
        for (; k < end; ++k) {
            int s = csr_src[k];
            float4 r = *(const float4*)(gin + (size_t)s * 32 + sub * 8);
            acc_half8(acc, r);
        }
#pragma unroll
        for (int i = 0; i < 8; ++i) sS[nl * 33 + sub * 8 + i] = acc[i];
    }
    __syncthreads();

    if (n >= N_NODES || sub != 0) return;
    float dv = dinv[n];
    float t[32];
#pragma unroll
    for (int kk = 0; kk < 32; ++kk)
        t[kk] = fmaxf(fmaf(dv, sS[nl * 33 + kk], sb[kk]), 0.0f);
    float o0 = sb2[0], o1 = sb2[1], o2 = sb2[2];
#pragma unroll
    for (int kk = 0; kk < 32; ++kk) {
        o0 = fmaf(t[kk], sW[kk * 3 + 0], o0);
        o1 = fmaf(t[kk], sW[kk * 3 + 1], o1);
        o2 = fmaf(t[kk], sW[kk * 3 + 2], o2);
    }
    out[(size_t)n * 3 + 0] = o0;
    out[(size_t)n * 3 + 1] = o1;
    out[(size_t)n * 3 + 2] = o2;
}

extern "C" void kernel_launch(void* const* d_in, const int* in_sizes, int n_in,
                              void* d_out, int out_size, void* d_ws, size_t ws_size,
                              hipStream_t stream) {
    const float* x    = (const float*)d_in[0];
    const int*   ei   = (const int*)d_in[1];
    const float* Wfc1 = (const float*)d_in[2];
    const float* bfc1 = (const float*)d_in[3];
    const float* Wc1  = (const float*)d_in[4];
    const float* bc1  = (const float*)d_in[5];
    const float* Wc2  = (const float*)d_in[6];
    const float* bc2  = (const float*)d_in[7];
    const float* Wc3  = (const float*)d_in[8];
    const float* bc3  = (const float*)d_in[9];
    const float* Wfc2 = (const float*)d_in[10];
    const float* bfc2 = (const float*)d_in[11];
    float* out = (float*)d_out;

    char* ws = (char*)d_ws;
    const size_t grow = (size_t)N_NODES * 32 * sizeof(__half);   // 6.4 MB
    size_t off = 0;
    __half* gA    = (__half*)(ws + off); off += grow;
    __half* gB    = (__half*)(ws + off); off += grow;
    int*   binned  = (int*)  (ws + off); off += (size_t)N_EDGES * sizeof(int);
    int*   csr_src = (int*)  (ws + off); off += (size_t)N_EDGES * sizeof(int);
    float* dinv    = (float*)(ws + off); off += (size_t)N_NODES * sizeof(float);
    int*   rowptr  = (int*)  (ws + off); off += (size_t)(N_NODES + 1) * sizeof(int);
    int*   blkbin  = (int*)  (ws + off); off += (size_t)NBUCK * NBLK * sizeof(int);
    int*   blkoff  = (int*)  (ws + off); off += (size_t)NBUCK * NBLK * sizeof(int);
    int*   bintot  = (int*)  (ws + off); off += (size_t)NBUCK * sizeof(int);
    int*   binoff  = (int*)  (ws + off); off += (size_t)(NBUCK + 1) * sizeof(int);

    const int nb_wave = (NBUCK + 3) / 4;              // 98
    const int nb_n = (N_NODES + 255) / 256;           // 391
    const int nb_f = (N_NODES * 4 + 255) / 256;       // 1563

    k_bincount<<<NBLK, 256, 0, stream>>>(ei, blkbin);
    k_bintot<<<nb_wave, 256, 0, stream>>>(blkbin, bintot);
    k_binscan<<<1, 512, 0, stream>>>(bintot, binoff);
    k_blkoff<<<nb_wave, 256, 0, stream>>>(blkbin, binoff, blkoff);
    k_binfill<<<NBLK, 256, 0, stream>>>(ei, blkoff, binned);
    k_sortdeg<<<NBUCK, 256, 0, stream>>>(binned, binoff, csr_src, rowptr, dinv);

    k_fc1_conv1<<<nb_n, 256, 0, stream>>>(x, Wfc1, bfc1, Wc1, dinv, gA);
    k_gather_mid<<<nb_f, 256, 0, stream>>>(rowptr, csr_src, gA, dinv, bc1, Wc2, gB);
    k_gather_mid<<<nb_f, 256, 0, stream>>>(rowptr, csr_src, gB, dinv, bc2, Wc3, gA);
    k_gather_out<<<nb_f, 256, 0, stream>>>(rowptr, csr_src, gA, dinv, bc3, Wfc2, bfc2, out);
}

// Round 6
// 267.784 us; speedup vs baseline: 6.5474x; 1.0129x over previous
//
#include <hip/hip_runtime.h>
#include <hip/hip_fp16.h>

// GCN: 100K nodes, 2.5M edges, dims 4 -> 32 -> (32x32 conv x3) -> 3.
// Round 6: src-partitioned TWO-PHASE gather. R5 FETCH (110MB/gather) showed the
// random g reads miss the 4MB per-XCD L2 (g = 6.4MB fp16). Counting sort now
// uses key = dst_local*2 + (src>=50K), giving per-node [rowptr, rowmid, next)
// segments. Phase A gathers src<50K (hot set 3.2MB = L2-resident) -> partial S;
// phase B gathers src>=50K + self + partial S, then fused MLP epilogue.
// Build stays atomic-free (LDS atomics only); g stays fp16, accumulate fp32.

constexpr int N_NODES = 100000;
constexpr int N_EDGES = 2500000;
constexpr int HALFN   = 50000;                             // src partition point
constexpr int BUCKET  = 256;
constexpr int NBUCK   = (N_NODES + BUCKET - 1) / BUCKET;   // 391
constexpr int NBLK    = 256;
constexpr int CHUNK   = (N_EDGES + NBLK - 1) / NBLK;       // 9766

// ================= build =================
__global__ __launch_bounds__(256) void k_bincount(const int* __restrict__ ei,
                                                  int* __restrict__ blkbin) {
    __shared__ int hist[NBUCK];
    for (int i = threadIdx.x; i < NBUCK; i += 256) hist[i] = 0;
    __syncthreads();
    int beg = blockIdx.x * CHUNK;
    int end = min(beg + CHUNK, N_EDGES);
    for (int e = beg + threadIdx.x; e < end; e += 256) {
        int d = ei[N_EDGES + e];
        atomicAdd(&hist[d >> 8], 1);
    }
    __syncthreads();
    for (int i = threadIdx.x; i < NBUCK; i += 256)
        blkbin[i * NBLK + blockIdx.x] = hist[i];
}

__global__ __launch_bounds__(256) void k_bintot(const int* __restrict__ blkbin,
                                                int* __restrict__ bintot) {
    int w = threadIdx.x >> 6, lane = threadIdx.x & 63;
    int bin = blockIdx.x * 4 + w;
    if (bin >= NBUCK) return;
    int s = 0;
    for (int k = lane; k < NBLK; k += 64) s += blkbin[bin * NBLK + k];
#pragma unroll
    for (int o = 32; o > 0; o >>= 1) s += __shfl_down(s, o);
    if (lane == 0) bintot[bin] = s;
}

__global__ __launch_bounds__(512) void k_binscan(const int* __restrict__ bintot,
                                                 int* __restrict__ binoff) {
    __shared__ int sc[512];
    int tid = threadIdx.x;
    int v = (tid < NBUCK) ? bintot[tid] : 0;
    sc[tid] = v;
    __syncthreads();
#pragma unroll
    for (int o = 1; o < 512; o <<= 1) {
        int t = (tid >= o) ? sc[tid - o] : 0;
        __syncthreads();
        sc[tid] += t;
        __syncthreads();
    }
    if (tid < NBUCK) binoff[tid] = sc[tid] - v;
    if (tid == NBUCK - 1) binoff[NBUCK] = sc[tid];
}

__global__ __launch_bounds__(256) void k_blkoff(const int* __restrict__ blkbin,
                                                const int* __restrict__ binoff,
                                                int* __restrict__ blkoff) {
    int w = threadIdx.x >> 6, lane = threadIdx.x & 63;
    int bin = blockIdx.x * 4 + w;
    if (bin >= NBUCK) return;
    int v[4];
#pragma unroll
    for (int i = 0; i < 4; ++i) v[i] = blkbin[bin * NBLK + lane * 4 + i];
    int mysum = v[0] + v[1] + v[2] + v[3];
    int pre = mysum;
#pragma unroll
    for (int o = 1; o < 64; o <<= 1) {
        int t = __shfl_up(pre, o);
        if (lane >= o) pre += t;
    }
    pre -= mysum;
    int run = binoff[bin] + pre;
#pragma unroll
    for (int i = 0; i < 4; ++i) {
        blkoff[bin * NBLK + lane * 4 + i] = run;
        run += v[i];
    }
}

__global__ __launch_bounds__(256) void k_binfill(const int* __restrict__ ei,
                                                 const int* __restrict__ blkoff,
                                                 int* __restrict__ binned) {
    __shared__ int cur[NBUCK];
    for (int i = threadIdx.x; i < NBUCK; i += 256)
        cur[i] = blkoff[i * NBLK + blockIdx.x];
    __syncthreads();
    int beg = blockIdx.x * CHUNK;
    int end = min(beg + CHUNK, N_EDGES);
    for (int e = beg + threadIdx.x; e < end; e += 256) {
        int s = ei[e];
        int d = ei[N_EDGES + e];
        int pos = atomicAdd(&cur[d >> 8], 1);
        binned[pos] = (s << 8) | (d & 255);
    }
}

// ---- within-bucket counting sort, key = dst_local*2 + (src>=HALFN) ----
// 512 threads, one key per thread. Produces rowptr, rowmid, dinv, csr_src.
__global__ __launch_bounds__(512) void k_sortdeg(const int* __restrict__ binned,
                                                 const int* __restrict__ binoff,
                                                 int* __restrict__ csr_src,
                                                 int* __restrict__ rowptr,
                                                 int* __restrict__ rowmid,
                                                 float* __restrict__ dinv) {
    __shared__ int cnt[512];
    __shared__ int sc[512];
    __shared__ int cur[512];
    int t = threadIdx.x;
    int b = blockIdx.x;
    int beg = binoff[b], end = binoff[b + 1];

    cnt[t] = 0;
    __syncthreads();
    for (int k = beg + t; k < end; k += 512) {
        int p = binned[k];
        int key = ((p & 255) << 1) | (((p >> 8) >= HALFN) ? 1 : 0);
        atomicAdd(&cnt[key], 1);
    }
    __syncthreads();

    int v = cnt[t];
    sc[t] = v;
    __syncthreads();
#pragma unroll
    for (int o = 1; o < 512; o <<= 1) {
        int tv = (t >= o) ? sc[t - o] : 0;
        __syncthreads();
        sc[t] += tv;
        __syncthreads();
    }
    int excl = sc[t] - v;
    cur[t] = excl;
    int dl = t >> 1;
    int n = b * 256 + dl;
    if (n < N_NODES) {
        if ((t & 1) == 0) {
            rowptr[n] = beg + excl;
            dinv[n] = rsqrtf((float)(cnt[t] + cnt[t + 1] + 1));  // +1 self-loop
        } else {
            rowmid[n] = beg + excl;
        }
    }
    if (b == NBUCK - 1 && t == 0) rowptr[N_NODES] = end;
    __syncthreads();

    for (int k = beg + t; k < end; k += 512) {
        int p = binned[k];
        int key = ((p & 255) << 1) | (((p >> 8) >= HALFN) ? 1 : 0);
        int pos = atomicAdd(&cur[key], 1);
        csr_src[beg + pos] = p >> 8;
    }
}

// ================= dense helpers =================
__device__ inline void store_half8(__half* p, const float* v) {
    __half2 h[4];
#pragma unroll
    for (int i = 0; i < 4; ++i)
        h[i] = __floats2half2_rn(v[2 * i], v[2 * i + 1]);
    *(float4*)p = *(float4*)h;
}

__device__ inline void acc_half8(float* acc, float4 raw) {
    __half2* hp = (__half2*)&raw;
#pragma unroll
    for (int i = 0; i < 4; ++i) {
        float2 f = __half22float2(hp[i]);
        acc[2 * i]     += f.x;
        acc[2 * i + 1] += f.y;
    }
}

// t = relu(x@Wfc1 + bfc1); g = half( dinv * (t@Wc1) )
__global__ __launch_bounds__(256) void k_fc1_conv1(
        const float* __restrict__ x,
        const float* __restrict__ Wfc1, const float* __restrict__ bfc1,
        const float* __restrict__ Wc1, const float* __restrict__ dinv,
        __half* __restrict__ g) {
    __shared__ float  sWf[128];
    __shared__ float  sbf[32];
    __shared__ float4 sW[256];
    if (threadIdx.x < 128) sWf[threadIdx.x] = Wfc1[threadIdx.x];
    if (threadIdx.x < 32)  sbf[threadIdx.x] = bfc1[threadIdx.x];
    sW[threadIdx.x] = ((const float4*)Wc1)[threadIdx.x];
    __syncthreads();

    int n = blockIdx.x * 256 + threadIdx.x;
    if (n >= N_NODES) return;

    float4 xin = *(const float4*)(x + (size_t)n * 4);
    float t[32];
#pragma unroll
    for (int j = 0; j < 32; ++j) {
        float a = fmaf(xin.x, sWf[j], sbf[j]);
        a = fmaf(xin.y, sWf[32 + j], a);
        a = fmaf(xin.z, sWf[64 + j], a);
        a = fmaf(xin.w, sWf[96 + j], a);
        t[j] = fmaxf(a, 0.0f);
    }
    float o[32];
#pragma unroll
    for (int j = 0; j < 32; ++j) o[j] = 0.f;
#pragma unroll
    for (int k = 0; k < 32; ++k) {
        float a = t[k];
#pragma unroll
        for (int q = 0; q < 8; ++q) {
            float4 w = sW[k * 8 + q];
            o[q * 4 + 0] = fmaf(a, w.x, o[q * 4 + 0]);
            o[q * 4 + 1] = fmaf(a, w.y, o[q * 4 + 1]);
            o[q * 4 + 2] = fmaf(a, w.z, o[q * 4 + 2]);
            o[q * 4 + 3] = fmaf(a, w.w, o[q * 4 + 3]);
        }
    }
    float dv = dinv[n];
#pragma unroll
    for (int j = 0; j < 32; ++j) o[j] *= dv;
    __half* gp = g + (size_t)n * 32;
    store_half8(gp,      o);
    store_half8(gp + 8,  o + 8);
    store_half8(gp + 16, o + 16);
    store_half8(gp + 24, o + 24);
}

// ---- phase A: Spart[n] = g[n] + sum_{src<HALFN} g[src]; hot set = g[0..HALFN) ----
__global__ __launch_bounds__(256) void k_gatherA(
        const int* __restrict__ rowptr, const int* __restrict__ rowmid,
        const int* __restrict__ csr_src, const __half* __restrict__ gin,
        float* __restrict__ Spart) {
    int tid = blockIdx.x * 256 + threadIdx.x;
    int n = tid >> 2;
    if (n >= N_NODES) return;
    int sub = tid & 3;
    float acc[8];
    float4 self = *(const float4*)(gin + (size_t)n * 32 + sub * 8);
    {
        __half2* hp = (__half2*)&self;
#pragma unroll
        for (int i = 0; i < 4; ++i) {
            float2 f = __half22float2(hp[i]);
            acc[2 * i] = f.x;
            acc[2 * i + 1] = f.y;
        }
    }
    int beg = rowptr[n], end = rowmid[n];
    int k = beg;
    for (; k + 3 < end; k += 4) {
        int s0 = csr_src[k], s1 = csr_src[k + 1];
        int s2 = csr_src[k + 2], s3 = csr_src[k + 3];
        float4 r0 = *(const float4*)(gin + (size_t)s0 * 32 + sub * 8);
        float4 r1 = *(const float4*)(gin + (size_t)s1 * 32 + sub * 8);
        float4 r2 = *(const float4*)(gin + (size_t)s2 * 32 + sub * 8);
        float4 r3 = *(const float4*)(gin + (size_t)s3 * 32 + sub * 8);
        acc_half8(acc, r0); acc_half8(acc, r1);
        acc_half8(acc, r2); acc_half8(acc, r3);
    }
    for (; k < end; ++k) {
        int s = csr_src[k];
        float4 r = *(const float4*)(gin + (size_t)s * 32 + sub * 8);
        acc_half8(acc, r);
    }
    float* sp = Spart + (size_t)n * 32 + sub * 8;
    *(float4*)sp = make_float4(acc[0], acc[1], acc[2], acc[3]);
    *(float4*)(sp + 4) = make_float4(acc[4], acc[5], acc[6], acc[7]);
}

// ---- phase B + mid MLP: S = Spart + sum_{src>=HALFN} g[src]; t=relu(dinv*S+b);
//      gout = half(dinv * t@W). Hot set = g[HALFN..N) ----
__global__ __launch_bounds__(256) void k_gatherB_mid(
        const int* __restrict__ rowptr, const int* __restrict__ rowmid,
        const int* __restrict__ csr_src, const __half* __restrict__ gin,
        const float* __restrict__ Spart, const float* __restrict__ dinv,
        const float* __restrict__ b, const float* __restrict__ W,
        __half* __restrict__ gout) {
    __shared__ float sS[64 * 33];
    __shared__ float sW[1024];
    __shared__ float sb[32];
    for (int i = threadIdx.x; i < 1024; i += 256) sW[i] = W[i];
    if (threadIdx.x < 32) sb[threadIdx.x] = b[threadIdx.x];

    int nl = threadIdx.x >> 2;
    int sub = threadIdx.x & 2 ? (threadIdx.x & 3) : (threadIdx.x & 3);  // = tid&3
    sub = threadIdx.x & 3;
    int n = blockIdx.x * 64 + nl;
    float acc[8];
    if (n < N_NODES) {
        const float* sp = Spart + (size_t)n * 32 + sub * 8;
        float4 p0 = *(const float4*)sp;
        float4 p1 = *(const float4*)(sp + 4);
        acc[0] = p0.x; acc[1] = p0.y; acc[2] = p0.z; acc[3] = p0.w;
        acc[4] = p1.x; acc[5] = p1.y; acc[6] = p1.z; acc[7] = p1.w;
        int beg = rowmid[n], end = rowptr[n + 1];
        int k = beg;
        for (; k + 3 < end; k += 4) {
            int s0 = csr_src[k], s1 = csr_src[k + 1];
            int s2 = csr_src[k + 2], s3 = csr_src[k + 3];
            float4 r0 = *(const float4*)(gin + (size_t)s0 * 32 + sub * 8);
            float4 r1 = *(const float4*)(gin + (size_t)s1 * 32 + sub * 8);
            float4 r2 = *(const float4*)(gin + (size_t)s2 * 32 + sub * 8);
            float4 r3 = *(const float4*)(gin + (size_t)s3 * 32 + sub * 8);
            acc_half8(acc, r0); acc_half8(acc, r1);
            acc_half8(acc, r2); acc_half8(acc, r3);
        }
        for (; k < end; ++k) {
            int s = csr_src[k];
            float4 r = *(const float4*)(gin + (size_t)s * 32 + sub * 8);
            acc_half8(acc, r);
        }
#pragma unroll
        for (int i = 0; i < 8; ++i) sS[nl * 33 + sub * 8 + i] = acc[i];
    }
    __syncthreads();

    if (n >= N_NODES) return;
    float dv = dinv[n];
    float t[32];
#pragma unroll
    for (int kk = 0; kk < 32; ++kk)
        t[kk] = fmaxf(fmaf(dv, sS[nl * 33 + kk], sb[kk]), 0.0f);
    float o[8];
#pragma unroll
    for (int j = 0; j < 8; ++j) o[j] = 0.f;
#pragma unroll
    for (int kk = 0; kk < 32; ++kk) {
        float a = t[kk];
#pragma unroll
        for (int j = 0; j < 8; ++j)
            o[j] = fmaf(a, sW[kk * 32 + sub * 8 + j], o[j]);
    }
#pragma unroll
    for (int j = 0; j < 8; ++j) o[j] *= dv;
    store_half8(gout + (size_t)n * 32 + sub * 8, o);
}

// ---- phase B + final layer ----
__global__ __launch_bounds__(256) void k_gatherB_out(
        const int* __restrict__ rowptr, const int* __restrict__ rowmid,
        const int* __restrict__ csr_src, const __half* __restrict__ gin,
        const float* __restrict__ Spart, const float* __restrict__ dinv,
        const float* __restrict__ bc3, const float* __restrict__ Wfc2,
        const float* __restrict__ bfc2, float* __restrict__ out) {
    __shared__ float sS[64 * 33];
    __shared__ float sW[96];
    __shared__ float sb[32];
    __shared__ float sb2[3];
    if (threadIdx.x < 96) sW[threadIdx.x] = Wfc2[threadIdx.x];
    if (threadIdx.x < 32) sb[threadIdx.x] = bc3[threadIdx.x];
    if (threadIdx.x < 3)  sb2[threadIdx.x] = bfc2[threadIdx.x];

    int nl = threadIdx.x >> 2;
    int sub = threadIdx.x & 3;
    int n = blockIdx.x * 64 + nl;
    float acc[8];
    if (n < N_NODES) {
        const float* sp = Spart + (size_t)n * 32 + sub * 8;
        float4 p0 = *(const float4*)sp;
        float4 p1 = *(const float4*)(sp + 4);
        acc[0] = p0.x; acc[1] = p0.y; acc[2] = p0.z; acc[3] = p0.w;
        acc[4] = p1.x; acc[5] = p1.y; acc[6] = p1.z; acc[7] = p1.w;
        int beg = rowmid[n], end = rowptr[n + 1];
        int k = beg;
        for (; k + 3 < end; k += 4) {
            int s0 = csr_src[k], s1 = csr_src[k + 1];
            int s2 = csr_src[k + 2], s3 = csr_src[k + 3];
            float4 r0 = *(const float4*)(gin + (size_t)s0 * 32 + sub * 8);
            float4 r1 = *(const float4*)(gin + (size_t)s1 * 32 + sub * 8);
            float4 r2 = *(const float4*)(gin + (size_t)s2 * 32 + sub * 8);
            float4 r3 = *(const float4*)(gin + (size_t)s3 * 32 + sub * 8);
            acc_half8(acc, r0); acc_half8(acc, r1);
            acc_half8(acc, r2); acc_half8(acc, r3);
        }
        for (; k < end; ++k) {
            int s = csr_src[k];
            float4 r = *(const float4*)(gin + (size_t)s * 32 + sub * 8);
            acc_half8(acc, r);
        }
#pragma unroll
        for (int i = 0; i < 8; ++i) sS[nl * 33 + sub * 8 + i] = acc[i];
    }
    __syncthreads();

    if (n >= N_NODES || sub != 0) return;
    float dv = dinv[n];
    float t[32];
#pragma unroll
    for (int kk = 0; kk < 32; ++kk)
        t[kk] = fmaxf(fmaf(dv, sS[nl * 33 + kk], sb[kk]), 0.0f);
    float o0 = sb2[0], o1 = sb2[1], o2 = sb2[2];
#pragma unroll
    for (int kk = 0; kk < 32; ++kk) {
        o0 = fmaf(t[kk], sW[kk * 3 + 0], o0);
        o1 = fmaf(t[kk], sW[kk * 3 + 1], o1);
        o2 = fmaf(t[kk], sW[kk * 3 + 2], o2);
    }
    out[(size_t)n * 3 + 0] = o0;
    out[(size_t)n * 3 + 1] = o1;
    out[(size_t)n * 3 + 2] = o2;
}

extern "C" void kernel_launch(void* const* d_in, const int* in_sizes, int n_in,
                              void* d_out, int out_size, void* d_ws, size_t ws_size,
                              hipStream_t stream) {
    const float* x    = (const float*)d_in[0];
    const int*   ei   = (const int*)d_in[1];
    const float* Wfc1 = (const float*)d_in[2];
    const float* bfc1 = (const float*)d_in[3];
    const float* Wc1  = (const float*)d_in[4];
    const float* bc1  = (const float*)d_in[5];
    const float* Wc2  = (const float*)d_in[6];
    const float* bc2  = (const float*)d_in[7];
    const float* Wc3  = (const float*)d_in[8];
    const float* bc3  = (const float*)d_in[9];
    const float* Wfc2 = (const float*)d_in[10];
    const float* bfc2 = (const float*)d_in[11];
    float* out = (float*)d_out;

    char* ws = (char*)d_ws;
    const size_t grow  = (size_t)N_NODES * 32 * sizeof(__half);   // 6.4 MB
    const size_t srow  = (size_t)N_NODES * 32 * sizeof(float);    // 12.8 MB
    size_t off = 0;
    __half* gA     = (__half*)(ws + off); off += grow;
    __half* gB     = (__half*)(ws + off); off += grow;
    float*  Spart  = (float*) (ws + off); off += srow;
    int*   binned  = (int*)  (ws + off); off += (size_t)N_EDGES * sizeof(int);
    int*   csr_src = (int*)  (ws + off); off += (size_t)N_EDGES * sizeof(int);
    float* dinv    = (float*)(ws + off); off += (size_t)N_NODES * sizeof(float);
    int*   rowptr  = (int*)  (ws + off); off += (size_t)(N_NODES + 1) * sizeof(int);
    int*   rowmid  = (int*)  (ws + off); off += (size_t)N_NODES * sizeof(int);
    int*   blkbin  = (int*)  (ws + off); off += (size_t)NBUCK * NBLK * sizeof(int);
    int*   blkoff  = (int*)  (ws + off); off += (size_t)NBUCK * NBLK * sizeof(int);
    int*   bintot  = (int*)  (ws + off); off += (size_t)NBUCK * sizeof(int);
    int*   binoff  = (int*)  (ws + off); off += (size_t)(NBUCK + 1) * sizeof(int);

    const int nb_wave = (NBUCK + 3) / 4;              // 98
    const int nb_n = (N_NODES + 255) / 256;           // 391
    const int nb_a = (N_NODES * 4 + 255) / 256;       // 1563 (4 thr/node)

    k_bincount<<<NBLK, 256, 0, stream>>>(ei, blkbin);
    k_bintot<<<nb_wave, 256, 0, stream>>>(blkbin, bintot);
    k_binscan<<<1, 512, 0, stream>>>(bintot, binoff);
    k_blkoff<<<nb_wave, 256, 0, stream>>>(blkbin, binoff, blkoff);
    k_binfill<<<NBLK, 256, 0, stream>>>(ei, blkoff, binned);
    k_sortdeg<<<NBUCK, 512, 0, stream>>>(binned, binoff, csr_src, rowptr, rowmid, dinv);

    k_fc1_conv1<<<nb_n, 256, 0, stream>>>(x, Wfc1, bfc1, Wc1, dinv, gA);

    k_gatherA<<<nb_a, 256, 0, stream>>>(rowptr, rowmid, csr_src, gA, Spart);
    k_gatherB_mid<<<nb_a, 256, 0, stream>>>(rowptr, rowmid, csr_src, gA, Spart, dinv, bc1, Wc2, gB);

    k_gatherA<<<nb_a, 256, 0, stream>>>(rowptr, rowmid, csr_src, gB, Spart);
    k_gatherB_mid<<<nb_a, 256, 0, stream>>>(rowptr, rowmid, csr_src, gB, Spart, dinv, bc2, Wc3, gA);

    k_gatherA<<<nb_a, 256, 0, stream>>>(rowptr, rowmid, csr_src, gA, Spart);
    k_gatherB_out<<<nb_a, 256, 0, stream>>>(rowptr, rowmid, csr_src, gA, Spart, dinv, bc3, Wfc2, bfc2, out);
}